// Round 5
// baseline (234.513 us; speedup 1.0000x reference)
//
#include <hip/hip_runtime.h>
#include <hip/hip_bf16.h>

#define B_ 8192
#define I_ 512
#define H_ 1024
#define R_ 64
#define PITCH 136   // shorts; 272 B rows, 16B-aligned; measured ~1.5cy/read conflict cost

typedef __bf16 bf16x8 __attribute__((ext_vector_type(8)));
typedef short  s16x8  __attribute__((ext_vector_type(8)));
typedef float  f32x4  __attribute__((ext_vector_type(4)));

static __device__ __forceinline__ short f2bf(float f) {
    union { float f; unsigned u; } v; v.f = f;
    unsigned r = v.u + 0x7fffu + ((v.u >> 16) & 1u);
    return (short)(r >> 16);
}
static __device__ __forceinline__ float sigmoidf_(float v) {
    return 1.f / (1.f + __expf(-v));
}
static __device__ __forceinline__ float tanhf_(float v) {
    return 2.f / (1.f + __expf(-2.f * v)) - 1.f;
}

// ---------------------------------------------------------------------------
// Prep: uxT[64][512], uhT[64][1024], Vc[4096][128] (all bf16), coef_x[4][512],
// coef_h[4][1024] (f32). Coef section: one wave per j, lanes = rank r,
// coalesced loads + shuffle reduction.
// Thread ranges: 32768 + 65536 + 524288 + 98304 = 720896 = 2816 * 256.
// ---------------------------------------------------------------------------
__global__ __launch_bounds__(256) void prep_kernel(
    const float* __restrict__ u_x, const float* __restrict__ u_h,
    const float* __restrict__ v_x, const float* __restrict__ v_h,
    short* __restrict__ uxT, short* __restrict__ uhT, short* __restrict__ Vc,
    float* __restrict__ coef_x, float* __restrict__ coef_h)
{
    int t = blockIdx.x * 256 + threadIdx.x;
    if (t < 64 * 512) {                       // uxT[r][k] = u_x[k][r], coalesced read
        int k = t >> 6, r = t & 63;
        uxT[r * 512 + k] = f2bf(u_x[t]);
        return;
    }
    t -= 64 * 512;
    if (t < 64 * 1024) {                      // uhT[r][k] = u_h[k][r]
        int k = t >> 6, r = t & 63;
        uhT[r * 1024 + k] = f2bf(u_h[t]);
        return;
    }
    t -= 64 * 1024;
    if (t < 4096 * 128) {                     // Vc = [v_x | v_h] rows, bf16
        int n = t >> 7, q = t & 127;
        Vc[t] = f2bf(q < 64 ? v_x[n * 64 + q] : v_h[n * 64 + (q - 64)]);
        return;
    }
    t -= 4096 * 128;
    // coef: 1536 waves, one j each (512 x-j, 1024 h-j)
    if (t < 1536 * 64) {
        const int wid = t >> 6, lane = t & 63;
        const float* U; const float* V; float* C; int j, JN;
        if (wid < 512) { U = u_x; V = v_x; C = coef_x; j = wid;       JN = 512;  }
        else           { U = u_h; V = v_h; C = coef_h; j = wid - 512; JN = 1024; }
        const float uv = U[(size_t)j * 64 + lane];
        float s[4];
#pragma unroll
        for (int g = 0; g < 4; ++g)
            s[g] = uv * V[(size_t)(g * H_ + j) * 64 + lane];
#pragma unroll
        for (int off = 32; off >= 1; off >>= 1)
#pragma unroll
            for (int g = 0; g < 4; ++g)
                s[g] += __shfl_xor(s[g], off, 64);
        if (lane == 0)
#pragma unroll
            for (int g = 0; g < 4; ++g)
                C[g * JN + j] = s[g];
        return;
    }
}

// ---------------------------------------------------------------------------
// Fused main kernel. Block = 1024 thr (16 waves), owns 64 batch rows.
// Phase 1 (P-phase): P[64][128] = [x@u_x | h@u_h] in bf16, kept in LDS.
//   Wave w = (mt = w&3: 16-row m-tile, nt = w>>2: 16-col n-tile of each half).
//   x/h chunks (64x128 fp32 -> bf16) staged coalesced into LDS At.
// Phase 2 (gate-phase, barrier-free): gates = P @ Vc^T + fused LSTM epilogue.
//   Wave w = (mt = w&3, jq = w>>2: 128-j range), 8 j-tiles of 16, with
//   epilogue operands (x,h,c) software-pipelined one tile ahead.
// Grid (B/64, 2): blockIdx.y = j-half (P computed redundantly, it's cheap).
// ---------------------------------------------------------------------------
__global__ __launch_bounds__(1024, 4) void main_kernel(
    const float* __restrict__ x, const float* __restrict__ h,
    const float* __restrict__ c,
    const short* __restrict__ uxT, const short* __restrict__ uhT,
    const short* __restrict__ Vc,
    const float* __restrict__ coef_x, const float* __restrict__ coef_h,
    const float* __restrict__ b_x, const float* __restrict__ b_h,
    const float* __restrict__ dia_x, const float* __restrict__ dia_h,
    float* __restrict__ out)
{
    __shared__ short At[64 * PITCH];    // staging chunk: 64 rows x 128 k
    __shared__ short Pl[64 * PITCH];    // P: 64 rows x 128 cols bf16

    const int w = threadIdx.x >> 6, lane = threadIdx.x & 63;
    const int quad = lane >> 4, lr = lane & 15;
    const int mt = w & 3;
    const int b0 = blockIdx.x * 64;

    const int srow = threadIdx.x >> 4;          // staging: 0..63
    const int scol = (threadIdx.x & 15) * 8;    // 0..120

    // ---------------- Phase 1: P into LDS ----------------
    {
        const int nt = w >> 2;                  // n-tile within each 64-half
        f32x4 accX = {}, accH = {};
        const short* arow = At + (mt * 16 + lr) * PITCH + quad * 8;

        // x-half: K=512
        for (int k0 = 0; k0 < I_; k0 += 128) {
            const float* src = x + (size_t)(b0 + srow) * I_ + k0 + scol;
            float4 v0 = ((const float4*)src)[0];
            float4 v1 = ((const float4*)src)[1];
            s16x8 p;
            p[0] = f2bf(v0.x); p[1] = f2bf(v0.y); p[2] = f2bf(v0.z); p[3] = f2bf(v0.w);
            p[4] = f2bf(v1.x); p[5] = f2bf(v1.y); p[6] = f2bf(v1.z); p[7] = f2bf(v1.w);
            __syncthreads();
            *(s16x8*)(At + srow * PITCH + scol) = p;
            __syncthreads();
#pragma unroll
            for (int ks = 0; ks < 4; ++ks) {
                bf16x8 bfrag = *(const bf16x8*)(uxT + (size_t)(nt * 16 + lr) * I_ + k0 + ks * 32 + quad * 8);
                bf16x8 afrag = *(const bf16x8*)(arow + ks * 32);
                accX = __builtin_amdgcn_mfma_f32_16x16x32_bf16(afrag, bfrag, accX, 0, 0, 0);
            }
        }
        // h-half: K=1024
        for (int k0 = 0; k0 < H_; k0 += 128) {
            const float* src = h + (size_t)(b0 + srow) * H_ + k0 + scol;
            float4 v0 = ((const float4*)src)[0];
            float4 v1 = ((const float4*)src)[1];
            s16x8 p;
            p[0] = f2bf(v0.x); p[1] = f2bf(v0.y); p[2] = f2bf(v0.z); p[3] = f2bf(v0.w);
            p[4] = f2bf(v1.x); p[5] = f2bf(v1.y); p[6] = f2bf(v1.z); p[7] = f2bf(v1.w);
            __syncthreads();
            *(s16x8*)(At + srow * PITCH + scol) = p;
            __syncthreads();
#pragma unroll
            for (int ks = 0; ks < 4; ++ks) {
                bf16x8 bfrag = *(const bf16x8*)(uhT + (size_t)(nt * 16 + lr) * H_ + k0 + ks * 32 + quad * 8);
                bf16x8 afrag = *(const bf16x8*)(arow + ks * 32);
                accH = __builtin_amdgcn_mfma_f32_16x16x32_bf16(afrag, bfrag, accH, 0, 0, 0);
            }
        }
        // write P: lane holds rows mt*16+quad*4+r, col nt*16+lr (C/D layout)
#pragma unroll
        for (int r = 0; r < 4; ++r) {
            short* dst = Pl + (mt * 16 + quad * 4 + r) * PITCH;
            dst[nt * 16 + lr]      = f2bf(accX[r]);
            dst[64 + nt * 16 + lr] = f2bf(accH[r]);
        }
        __syncthreads();
    }

    // ---------------- Phase 2: gates + epilogue (barrier-free) ----------------
    const int jq = w >> 2;
    int j0 = blockIdx.y * 512 + jq * 128;       // 8 tiles of 16 j

    // prefetch epilogue operands for first tile
    float xv[4], hv[4], cv[4];
    {
        const int j = j0 + lr;
        const bool jx = (j < I_);
#pragma unroll
        for (int r = 0; r < 4; ++r) {
            const int brow = b0 + mt * 16 + quad * 4 + r;
            cv[r] = c[(size_t)brow * H_ + j];
            hv[r] = h[(size_t)brow * H_ + j];
            xv[r] = jx ? x[(size_t)brow * I_ + j] : 0.f;
        }
    }

    const short* prow = Pl + (mt * 16 + lr) * PITCH;

    for (int tt = 0; tt < 8; ++tt) {
        const int j = j0 + lr;
        const bool jx = (j < I_);

        // small per-j operands (L1/L2-hot)
        const float dx = jx ? dia_x[j] : 0.f;
        const float dh = dia_h[j];
        float cx[4], ch[4], bsum[4];
#pragma unroll
        for (int g = 0; g < 4; ++g) {
            cx[g]   = jx ? coef_x[g * I_ + j] : 0.f;
            ch[g]   = coef_h[g * H_ + j];
            bsum[g] = b_x[g * H_ + j] + b_h[g * H_ + j];
        }

        // MFMA: A from LDS (P), B gathered from Vc (L2-hot)
        f32x4 acc[4] = {};
#pragma unroll
        for (int ks = 0; ks < 4; ++ks) {
            bf16x8 a = *(const bf16x8*)(prow + ks * 32 + quad * 8);
#pragma unroll
            for (int g = 0; g < 4; ++g) {
                bf16x8 b = *(const bf16x8*)(Vc + (size_t)(g * H_ + j0 + lr) * 128 + ks * 32 + quad * 8);
                acc[g] = __builtin_amdgcn_mfma_f32_16x16x32_bf16(a, b, acc[g], 0, 0, 0);
            }
        }

        // prefetch next tile's epilogue operands (overlaps with epilogue VALU)
        float xn[4], hn[4], cn_[4];
        if (tt < 7) {
            const int jn = j0 + 16 + lr;
            const bool jnx = (jn < I_);
#pragma unroll
            for (int r = 0; r < 4; ++r) {
                const int brow = b0 + mt * 16 + quad * 4 + r;
                cn_[r] = c[(size_t)brow * H_ + jn];
                hn[r]  = h[(size_t)brow * H_ + jn];
                xn[r]  = jnx ? x[(size_t)brow * I_ + jn] : 0.f;
            }
        }

        // epilogue
#pragma unroll
        for (int r = 0; r < 4; ++r) {
            const int brow = b0 + mt * 16 + quad * 4 + r;
            const float xe = xv[r], he = hv[r];
            const float z  = dx * xe + dh * he;

            const float g0 = acc[0][r] - xe * cx[0] - he * ch[0] + bsum[0] + z;
            const float g1 = acc[1][r] - xe * cx[1] - he * ch[1] + bsum[1] + z;
            const float g2 = acc[2][r] - xe * cx[2] - he * ch[2] + bsum[2] + z;
            const float g3 = acc[3][r] - xe * cx[3] - he * ch[3] + bsum[3] + z;

            const float ig = sigmoidf_(g0);
            const float fg = sigmoidf_(g1);
            const float og = sigmoidf_(g2);
            const float ng = tanhf_(g3);

            const float cn = fg * cv[r] + ig * ng;
            const float hnv = og * tanhf_(cn);

            out[(size_t)brow * H_ + j] = hnv;
            out[(size_t)B_ * H_ + (size_t)brow * H_ + j] = cn;
        }

#pragma unroll
        for (int r = 0; r < 4; ++r) { xv[r] = xn[r]; hv[r] = hn[r]; cv[r] = cn_[r]; }
        j0 += 16;
    }
}

// ---------------------------------------------------------------------------
extern "C" void kernel_launch(void* const* d_in, const int* in_sizes, int n_in,
                              void* d_out, int out_size, void* d_ws, size_t ws_size,
                              hipStream_t stream) {
    const float* x     = (const float*)d_in[0];
    const float* h     = (const float*)d_in[1];
    const float* c     = (const float*)d_in[2];
    const float* u_x   = (const float*)d_in[3];
    const float* u_h   = (const float*)d_in[4];
    const float* v_x   = (const float*)d_in[5];
    const float* v_h   = (const float*)d_in[6];
    const float* b_x   = (const float*)d_in[7];
    const float* b_h   = (const float*)d_in[8];
    const float* dia_x = (const float*)d_in[9];
    const float* dia_h = (const float*)d_in[10];
    float* out = (float*)d_out;

    char* ws = (char*)d_ws;
    short* uxT    = (short*)(ws);                          //    65,536 B
    short* uhT    = (short*)(ws + 65536);                  //   131,072
    short* Vc     = (short*)(ws + 65536 + 131072);         // 1,048,576
    float* coef_x = (float*)(ws + 65536 + 131072 + 1048576);          // 8,192
    float* coef_h = (float*)(ws + 65536 + 131072 + 1048576 + 8192);   // 16,384

    prep_kernel<<<2816, 256, 0, stream>>>(u_x, u_h, v_x, v_h, uxT, uhT, Vc, coef_x, coef_h);
    main_kernel<<<dim3(128, 2), 1024, 0, stream>>>(x, h, c, uxT, uhT, Vc,
                                                   coef_x, coef_h, b_x, b_h,
                                                   dia_x, dia_h, out);
}

// Round 6
// 229.571 us; speedup vs baseline: 1.0215x; 1.0215x over previous
//
#include <hip/hip_runtime.h>
#include <hip/hip_bf16.h>

#define B_ 8192
#define I_ 512
#define H_ 1024
#define R_ 64

typedef __bf16 bf16x8 __attribute__((ext_vector_type(8)));
typedef short  s16x8  __attribute__((ext_vector_type(8)));
typedef float  f32x4  __attribute__((ext_vector_type(4)));

static __device__ __forceinline__ short f2bf(float f) {
    union { float f; unsigned u; } v; v.f = f;
    unsigned r = v.u + 0x7fffu + ((v.u >> 16) & 1u);
    return (short)(r >> 16);
}
static __device__ __forceinline__ float sigmoidf_(float v) {
    return 1.f / (1.f + __expf(-v));
}
static __device__ __forceinline__ float tanhf_(float v) {
    return 2.f / (1.f + __expf(-2.f * v)) - 1.f;
}

// ---------------------------------------------------------------------------
// Prep: uxT[64][512], uhT[64][1024], Vc[4096][128] (all bf16), coef_x[4][512],
// coef_h[4][1024] (f32). Coef section: one wave per j, lanes = rank r.
// 32768 + 65536 + 524288 + 98304 = 720896 = 2816 * 256 threads.
// ---------------------------------------------------------------------------
__global__ __launch_bounds__(256) void prep_kernel(
    const float* __restrict__ u_x, const float* __restrict__ u_h,
    const float* __restrict__ v_x, const float* __restrict__ v_h,
    short* __restrict__ uxT, short* __restrict__ uhT, short* __restrict__ Vc,
    float* __restrict__ coef_x, float* __restrict__ coef_h)
{
    int t = blockIdx.x * 256 + threadIdx.x;
    if (t < 64 * 512) {                       // uxT[r][k] = u_x[k][r], coalesced read
        int k = t >> 6, r = t & 63;
        uxT[r * 512 + k] = f2bf(u_x[t]);
        return;
    }
    t -= 64 * 512;
    if (t < 64 * 1024) {                      // uhT[r][k] = u_h[k][r]
        int k = t >> 6, r = t & 63;
        uhT[r * 1024 + k] = f2bf(u_h[t]);
        return;
    }
    t -= 64 * 1024;
    if (t < 4096 * 128) {                     // Vc = [v_x | v_h] rows, bf16
        int n = t >> 7, q = t & 127;
        Vc[t] = f2bf(q < 64 ? v_x[n * 64 + q] : v_h[n * 64 + (q - 64)]);
        return;
    }
    t -= 4096 * 128;
    if (t < 1536 * 64) {                      // coef: 1536 waves, one j each
        const int wid = t >> 6, lane = t & 63;
        const float* U; const float* V; float* C; int j, JN;
        if (wid < 512) { U = u_x; V = v_x; C = coef_x; j = wid;       JN = 512;  }
        else           { U = u_h; V = v_h; C = coef_h; j = wid - 512; JN = 1024; }
        const float uv = U[(size_t)j * 64 + lane];
        float s[4];
#pragma unroll
        for (int g = 0; g < 4; ++g)
            s[g] = uv * V[(size_t)(g * H_ + j) * 64 + lane];
#pragma unroll
        for (int off = 32; off >= 1; off >>= 1)
#pragma unroll
            for (int g = 0; g < 4; ++g)
                s[g] += __shfl_xor(s[g], off, 64);
        if (lane == 0)
#pragma unroll
            for (int g = 0; g < 4; ++g)
                C[g * JN + j] = s[g];
        return;
    }
}

// ---------------------------------------------------------------------------
// Stage 1: P[b][0:64] = x @ u_x, P[b][64:128] = h @ u_h  (bf16 MFMA).
// 256-thr blocks (4 waves), 16 batch rows per block -> grid (512, 2) = 1024
// blocks (~4/CU: per-chunk barriers overlap across blocks). Next chunk's
// global loads prefetched before current chunk's MFMAs.
// ---------------------------------------------------------------------------
__global__ __launch_bounds__(256) void stage1_kernel(
    const float* __restrict__ x, const float* __restrict__ h,
    const short* __restrict__ uxT, const short* __restrict__ uhT,
    short* __restrict__ P)
{
    __shared__ short At[16 * 136];   // 16 rows x 128-k chunk, pitch 136
    const int w = threadIdx.x >> 6, lane = threadIdx.x & 63;
    const int quad = lane >> 4, lr = lane & 15;
    const int n0 = w * 16;

    const float* X; const short* UT; int K, co;
    if (blockIdx.y == 0) { X = x; UT = uxT; K = I_; co = 0; }
    else                 { X = h; UT = uhT; K = H_; co = 64; }

    const int b0 = blockIdx.x * 16;
    const int srow = threadIdx.x >> 4;          // 0..15
    const int scol = (threadIdx.x & 15) * 8;    // 0..120

    f32x4 acc = {};
    const short* bp = UT + (size_t)(n0 + lr) * K + quad * 8;
    const short* arow = At + lr * 136 + quad * 8;
    const float* srcbase = X + (size_t)(b0 + srow) * K + scol;

    float4 c0 = ((const float4*)(srcbase))[0];
    float4 c1 = ((const float4*)(srcbase))[1];

    for (int k0 = 0; k0 < K; k0 += 128) {
        s16x8 p;
        p[0] = f2bf(c0.x); p[1] = f2bf(c0.y); p[2] = f2bf(c0.z); p[3] = f2bf(c0.w);
        p[4] = f2bf(c1.x); p[5] = f2bf(c1.y); p[6] = f2bf(c1.z); p[7] = f2bf(c1.w);
        __syncthreads();               // previous chunk fully consumed
        *(s16x8*)(At + srow * 136 + scol) = p;
        __syncthreads();
        if (k0 + 128 < K) {            // prefetch next chunk (overlaps MFMAs)
            c0 = ((const float4*)(srcbase + k0 + 128))[0];
            c1 = ((const float4*)(srcbase + k0 + 128))[1];
        }
#pragma unroll
        for (int ks = 0; ks < 4; ++ks) {
            bf16x8 bfrag = *(const bf16x8*)(bp + k0 + ks * 32);
            bf16x8 afrag = *(const bf16x8*)(arow + ks * 32);
            acc = __builtin_amdgcn_mfma_f32_16x16x32_bf16(afrag, bfrag, acc, 0, 0, 0);
        }
    }

#pragma unroll
    for (int r = 0; r < 4; ++r)
        P[(size_t)(b0 + quad * 4 + r) * 128 + co + n0 + lr] = f2bf(acc[r]);
}

// ---------------------------------------------------------------------------
// Stage 2: gates = P @ Vc^T with fused LSTM epilogue.
// 64-thr single-wave blocks, NO LDS, NO barriers -> fully independent waves.
// Wave = 64 rows x 16 j; the 4 m-tiles (16 rows) sequential: acc = 16 AGPRs.
// A-fragments + epilogue operands pipelined one m-tile ahead; Vc B-fragments
// re-gathered per m-tile (16 KB tile, L1/L2-hot). Grid (B/64, H/16).
// ---------------------------------------------------------------------------
__global__ __launch_bounds__(64) void stage2_kernel(
    const short* __restrict__ P, const short* __restrict__ Vc,
    const float* __restrict__ x, const float* __restrict__ h,
    const float* __restrict__ c,
    const float* __restrict__ coef_x, const float* __restrict__ coef_h,
    const float* __restrict__ b_x, const float* __restrict__ b_h,
    const float* __restrict__ dia_x, const float* __restrict__ dia_h,
    float* __restrict__ out)
{
    const int lane = threadIdx.x;
    const int quad = lane >> 4, lr = lane & 15;
    const int b0 = blockIdx.x * 64;
    const int j0 = blockIdx.y * 16;
    const int j = j0 + lr;
    const bool jx = (j < I_);

    // per-j (lane-constant) small operands — L2-hot
    const float dx = jx ? dia_x[j] : 0.f;
    const float dh = dia_h[j];
    float cx[4], ch[4], bsum[4];
#pragma unroll
    for (int g = 0; g < 4; ++g) {
        cx[g]   = jx ? coef_x[g * I_ + j] : 0.f;
        ch[g]   = coef_h[g * H_ + j];
        bsum[g] = b_x[g * H_ + j] + b_h[g * H_ + j];
    }

    // prologue: A-fragments + epilogue operands for m-tile 0
    bf16x8 a[4];
#pragma unroll
    for (int ks = 0; ks < 4; ++ks)
        a[ks] = *(const bf16x8*)(P + (size_t)(b0 + lr) * 128 + ks * 32 + quad * 8);
    float xv[4], hv[4], cv[4];
#pragma unroll
    for (int r = 0; r < 4; ++r) {
        const int brow = b0 + quad * 4 + r;
        cv[r] = c[(size_t)brow * H_ + j];
        hv[r] = h[(size_t)brow * H_ + j];
        xv[r] = jx ? x[(size_t)brow * I_ + j] : 0.f;
    }

#pragma unroll
    for (int mt = 0; mt < 4; ++mt) {
        // prefetch next m-tile's A-fragments + epilogue operands
        bf16x8 an[4];
        float xn[4], hn[4], cn2[4];
        if (mt < 3) {
            const int rb = b0 + (mt + 1) * 16;
#pragma unroll
            for (int ks = 0; ks < 4; ++ks)
                an[ks] = *(const bf16x8*)(P + (size_t)(rb + lr) * 128 + ks * 32 + quad * 8);
#pragma unroll
            for (int r = 0; r < 4; ++r) {
                const int brow = rb + quad * 4 + r;
                cn2[r] = c[(size_t)brow * H_ + j];
                hn[r]  = h[(size_t)brow * H_ + j];
                xn[r]  = jx ? x[(size_t)brow * I_ + j] : 0.f;
            }
        }

        // MFMA: B gathered fresh per m-tile (same addresses each mt -> cache-hot)
        f32x4 acc[4] = {};
#pragma unroll
        for (int ks = 0; ks < 4; ++ks) {
#pragma unroll
            for (int g = 0; g < 4; ++g) {
                bf16x8 b = *(const bf16x8*)(Vc + (size_t)(g * H_ + j0 + lr) * 128 + ks * 32 + quad * 8);
                acc[g] = __builtin_amdgcn_mfma_f32_16x16x32_bf16(a[ks], b, acc[g], 0, 0, 0);
            }
        }

        // epilogue for this m-tile
#pragma unroll
        for (int r = 0; r < 4; ++r) {
            const int brow = b0 + mt * 16 + quad * 4 + r;
            const float xe = xv[r], he = hv[r];
            const float z  = dx * xe + dh * he;

            const float g0 = acc[0][r] - xe * cx[0] - he * ch[0] + bsum[0] + z;
            const float g1 = acc[1][r] - xe * cx[1] - he * ch[1] + bsum[1] + z;
            const float g2 = acc[2][r] - xe * cx[2] - he * ch[2] + bsum[2] + z;
            const float g3 = acc[3][r] - xe * cx[3] - he * ch[3] + bsum[3] + z;

            const float ig = sigmoidf_(g0);
            const float fg = sigmoidf_(g1);
            const float og = sigmoidf_(g2);
            const float ng = tanhf_(g3);

            const float cn = fg * cv[r] + ig * ng;
            const float hnv = og * tanhf_(cn);

            out[(size_t)brow * H_ + j] = hnv;
            out[(size_t)B_ * H_ + (size_t)brow * H_ + j] = cn;
        }

        if (mt < 3) {
#pragma unroll
            for (int ks = 0; ks < 4; ++ks) a[ks] = an[ks];
#pragma unroll
            for (int r = 0; r < 4; ++r) { xv[r] = xn[r]; hv[r] = hn[r]; cv[r] = cn2[r]; }
        }
    }
}

// ---------------------------------------------------------------------------
extern "C" void kernel_launch(void* const* d_in, const int* in_sizes, int n_in,
                              void* d_out, int out_size, void* d_ws, size_t ws_size,
                              hipStream_t stream) {
    const float* x     = (const float*)d_in[0];
    const float* h     = (const float*)d_in[1];
    const float* c     = (const float*)d_in[2];
    const float* u_x   = (const float*)d_in[3];
    const float* u_h   = (const float*)d_in[4];
    const float* v_x   = (const float*)d_in[5];
    const float* v_h   = (const float*)d_in[6];
    const float* b_x   = (const float*)d_in[7];
    const float* b_h   = (const float*)d_in[8];
    const float* dia_x = (const float*)d_in[9];
    const float* dia_h = (const float*)d_in[10];
    float* out = (float*)d_out;

    char* ws = (char*)d_ws;
    short* P      = (short*)(ws);                                    // 2,097,152 B
    short* uxT    = (short*)(ws + 2097152);                          //    65,536
    short* uhT    = (short*)(ws + 2097152 + 65536);                  //   131,072
    short* Vc     = (short*)(ws + 2097152 + 65536 + 131072);         // 1,048,576
    float* coef_x = (float*)(ws + 2097152 + 65536 + 131072 + 1048576);
    float* coef_h = (float*)(ws + 2097152 + 65536 + 131072 + 1048576 + 8192);

    prep_kernel<<<2816, 256, 0, stream>>>(u_x, u_h, v_x, v_h, uxT, uhT, Vc, coef_x, coef_h);
    stage1_kernel<<<dim3(512, 2), 256, 0, stream>>>(x, h, uxT, uhT, P);
    stage2_kernel<<<dim3(128, 64), 64, 0, stream>>>(P, Vc, x, h, c,
                                                    coef_x, coef_h, b_x, b_h,
                                                    dia_x, dia_h, out);
}

// Round 7
// 194.378 us; speedup vs baseline: 1.2065x; 1.1811x over previous
//
#include <hip/hip_runtime.h>
#include <hip/hip_bf16.h>

#define B_ 8192
#define I_ 512
#define H_ 1024
#define R_ 64

typedef __bf16 bf16x8 __attribute__((ext_vector_type(8)));
typedef short  s16x8  __attribute__((ext_vector_type(8)));
typedef float  f32x4  __attribute__((ext_vector_type(4)));

static __device__ __forceinline__ short f2bf(float f) {
    union { float f; unsigned u; } v; v.f = f;
    unsigned r = v.u + 0x7fffu + ((v.u >> 16) & 1u);
    return (short)(r >> 16);
}
static __device__ __forceinline__ float sigmoidf_(float v) {
    return 1.f / (1.f + __expf(-v));
}
static __device__ __forceinline__ float tanhf_(float v) {
    return 2.f / (1.f + __expf(-2.f * v)) - 1.f;
}

// ---------------------------------------------------------------------------
// Prep: uxT[64][512], uhT[64][1024], Vc[4096][128] (all bf16), coef_x[4][512],
// coef_h[4][1024] (f32). Coef section: one wave per j, lanes = rank r.
// 32768 + 65536 + 524288 + 98304 = 720896 = 2816 * 256 threads.
// ---------------------------------------------------------------------------
__global__ __launch_bounds__(256) void prep_kernel(
    const float* __restrict__ u_x, const float* __restrict__ u_h,
    const float* __restrict__ v_x, const float* __restrict__ v_h,
    short* __restrict__ uxT, short* __restrict__ uhT, short* __restrict__ Vc,
    float* __restrict__ coef_x, float* __restrict__ coef_h)
{
    int t = blockIdx.x * 256 + threadIdx.x;
    if (t < 64 * 512) {                       // uxT[r][k] = u_x[k][r], coalesced read
        int k = t >> 6, r = t & 63;
        uxT[r * 512 + k] = f2bf(u_x[t]);
        return;
    }
    t -= 64 * 512;
    if (t < 64 * 1024) {                      // uhT[r][k] = u_h[k][r]
        int k = t >> 6, r = t & 63;
        uhT[r * 1024 + k] = f2bf(u_h[t]);
        return;
    }
    t -= 64 * 1024;
    if (t < 4096 * 128) {                     // Vc = [v_x | v_h] rows, bf16
        int n = t >> 7, q = t & 127;
        Vc[t] = f2bf(q < 64 ? v_x[n * 64 + q] : v_h[n * 64 + (q - 64)]);
        return;
    }
    t -= 4096 * 128;
    if (t < 1536 * 64) {                      // coef: 1536 waves, one j each
        const int wid = t >> 6, lane = t & 63;
        const float* U; const float* V; float* C; int j, JN;
        if (wid < 512) { U = u_x; V = v_x; C = coef_x; j = wid;       JN = 512;  }
        else           { U = u_h; V = v_h; C = coef_h; j = wid - 512; JN = 1024; }
        const float uv = U[(size_t)j * 64 + lane];
        float s[4];
#pragma unroll
        for (int g = 0; g < 4; ++g)
            s[g] = uv * V[(size_t)(g * H_ + j) * 64 + lane];
#pragma unroll
        for (int off = 32; off >= 1; off >>= 1)
#pragma unroll
            for (int g = 0; g < 4; ++g)
                s[g] += __shfl_xor(s[g], off, 64);
        if (lane == 0)
#pragma unroll
            for (int g = 0; g < 4; ++g)
                C[g * JN + j] = s[g];
        return;
    }
}

// ---------------------------------------------------------------------------
// Stage 1: P[b][0:64] = x @ u_x, P[b][64:128] = h @ u_h  (bf16 MFMA).
// 256-thr blocks (4 waves), 16 batch rows per block -> grid (512, 2).
// Next chunk's global loads prefetched before current chunk's MFMAs.
// ---------------------------------------------------------------------------
__global__ __launch_bounds__(256) void stage1_kernel(
    const float* __restrict__ x, const float* __restrict__ h,
    const short* __restrict__ uxT, const short* __restrict__ uhT,
    short* __restrict__ P)
{
    __shared__ short At[16 * 136];
    const int w = threadIdx.x >> 6, lane = threadIdx.x & 63;
    const int quad = lane >> 4, lr = lane & 15;
    const int n0 = w * 16;

    const float* X; const short* UT; int K, co;
    if (blockIdx.y == 0) { X = x; UT = uxT; K = I_; co = 0; }
    else                 { X = h; UT = uhT; K = H_; co = 64; }

    const int b0 = blockIdx.x * 16;
    const int srow = threadIdx.x >> 4;
    const int scol = (threadIdx.x & 15) * 8;

    f32x4 acc = {};
    const short* bp = UT + (size_t)(n0 + lr) * K + quad * 8;
    const short* arow = At + lr * 136 + quad * 8;
    const float* srcbase = X + (size_t)(b0 + srow) * K + scol;

    float4 c0 = ((const float4*)(srcbase))[0];
    float4 c1 = ((const float4*)(srcbase))[1];

    for (int k0 = 0; k0 < K; k0 += 128) {
        s16x8 p;
        p[0] = f2bf(c0.x); p[1] = f2bf(c0.y); p[2] = f2bf(c0.z); p[3] = f2bf(c0.w);
        p[4] = f2bf(c1.x); p[5] = f2bf(c1.y); p[6] = f2bf(c1.z); p[7] = f2bf(c1.w);
        __syncthreads();
        *(s16x8*)(At + srow * 136 + scol) = p;
        __syncthreads();
        if (k0 + 128 < K) {
            c0 = ((const float4*)(srcbase + k0 + 128))[0];
            c1 = ((const float4*)(srcbase + k0 + 128))[1];
        }
#pragma unroll
        for (int ks = 0; ks < 4; ++ks) {
            bf16x8 bfrag = *(const bf16x8*)(bp + k0 + ks * 32);
            bf16x8 afrag = *(const bf16x8*)(arow + ks * 32);
            acc = __builtin_amdgcn_mfma_f32_16x16x32_bf16(afrag, bfrag, acc, 0, 0, 0);
        }
    }

#pragma unroll
    for (int r = 0; r < 4; ++r)
        P[(size_t)(b0 + quad * 4 + r) * 128 + co + n0 + lr] = f2bf(acc[r]);
}

// ---------------------------------------------------------------------------
// Stage 2: gates = P @ Vc^T with fused LSTM epilogue.
// Block = 256 thr (4 waves). Vc j-tile (4 gates x 16 j x 128 k, 17 KB) staged
// ONCE into LDS (the R4 winner; R6 showed global B-gather thrashes L1).
// Wave owns 128 rows = 8 m-tiles of 16, processed sequentially with A-frag
// (P, L2-hot) and epilogue x/h/c prefetched ONE M-TILE AHEAD so global
// latency hides under the previous tile's MFMA + epilogue VALU.
// Grid (B/512, H/16) = (16, 64) = 1024 blocks = 4/CU (one residency round).
// ---------------------------------------------------------------------------
__global__ __launch_bounds__(256, 3) void stage2_kernel(
    const short* __restrict__ P, const short* __restrict__ Vc,
    const float* __restrict__ x, const float* __restrict__ h,
    const float* __restrict__ c,
    const float* __restrict__ coef_x, const float* __restrict__ coef_h,
    const float* __restrict__ b_x, const float* __restrict__ b_h,
    const float* __restrict__ dia_x, const float* __restrict__ dia_h,
    float* __restrict__ out)
{
    __shared__ short Bt[4 * 16 * 136];   // [gate][j-row][k], pitch 136 (2-way banks, ~free)
    const int w = threadIdx.x >> 6, lane = threadIdx.x & 63;
    const int quad = lane >> 4, lr = lane & 15;
    const int b0 = blockIdx.x * 512 + w * 128;
    const int j0 = blockIdx.y * 16;
    const int j = j0 + lr;
    const bool jx = (j < I_);

    // stage Vc tile: 64 rows (4 gates x 16 j) x 128 k, 64 B per thread
    {
        const int row = threadIdx.x >> 2;          // 0..63
        const int g = row >> 4, jj = row & 15;
        const int col = (threadIdx.x & 3) * 32;
        const short* src = Vc + (size_t)(g * H_ + j0 + jj) * 128 + col;
        short* dst = Bt + (g * 16 + jj) * 136 + col;
        *(s16x8*)(dst)      = *(const s16x8*)(src);
        *(s16x8*)(dst + 8)  = *(const s16x8*)(src + 8);
        *(s16x8*)(dst + 16) = *(const s16x8*)(src + 16);
        *(s16x8*)(dst + 24) = *(const s16x8*)(src + 24);
    }

    // per-j (lane-constant) small operands — L2-hot
    const float dx = jx ? dia_x[j] : 0.f;
    const float dh = dia_h[j];
    float cx[4], ch[4], bsum[4];
#pragma unroll
    for (int g = 0; g < 4; ++g) {
        cx[g]   = jx ? coef_x[g * I_ + j] : 0.f;
        ch[g]   = coef_h[g * H_ + j];
        bsum[g] = b_x[g * H_ + j] + b_h[g * H_ + j];
    }
    __syncthreads();

    // prologue: A-fragments + epilogue operands for m-tile 0
    bf16x8 a[4];
#pragma unroll
    for (int ks = 0; ks < 4; ++ks)
        a[ks] = *(const bf16x8*)(P + (size_t)(b0 + lr) * 128 + ks * 32 + quad * 8);
    float xv[4], hv[4], cv[4];
#pragma unroll
    for (int r = 0; r < 4; ++r) {
        const int brow = b0 + quad * 4 + r;
        cv[r] = c[(size_t)brow * H_ + j];
        hv[r] = h[(size_t)brow * H_ + j];
        xv[r] = jx ? x[(size_t)brow * I_ + j] : 0.f;
    }

    for (int mt = 0; mt < 8; ++mt) {
        // prefetch next m-tile's A-fragments + epilogue operands (overlap MFMA+epi)
        bf16x8 an[4];
        float xn[4], hn[4], cn2[4];
        if (mt < 7) {
            const int rb = b0 + (mt + 1) * 16;
#pragma unroll
            for (int ks = 0; ks < 4; ++ks)
                an[ks] = *(const bf16x8*)(P + (size_t)(rb + lr) * 128 + ks * 32 + quad * 8);
#pragma unroll
            for (int r = 0; r < 4; ++r) {
                const int brow = rb + quad * 4 + r;
                cn2[r] = c[(size_t)brow * H_ + j];
                hn[r]  = h[(size_t)brow * H_ + j];
                xn[r]  = jx ? x[(size_t)brow * I_ + j] : 0.f;
            }
        }

        // MFMA: A from regs (prefetched), B from LDS
        f32x4 acc[4] = {};
#pragma unroll
        for (int ks = 0; ks < 4; ++ks) {
#pragma unroll
            for (int g = 0; g < 4; ++g) {
                bf16x8 b = *(const bf16x8*)(Bt + (g * 16 + lr) * 136 + ks * 32 + quad * 8);
                acc[g] = __builtin_amdgcn_mfma_f32_16x16x32_bf16(a[ks], b, acc[g], 0, 0, 0);
            }
        }

        // epilogue for this m-tile
#pragma unroll
        for (int r = 0; r < 4; ++r) {
            const int brow = b0 + mt * 16 + quad * 4 + r;
            const float xe = xv[r], he = hv[r];
            const float z  = dx * xe + dh * he;

            const float g0 = acc[0][r] - xe * cx[0] - he * ch[0] + bsum[0] + z;
            const float g1 = acc[1][r] - xe * cx[1] - he * ch[1] + bsum[1] + z;
            const float g2 = acc[2][r] - xe * cx[2] - he * ch[2] + bsum[2] + z;
            const float g3 = acc[3][r] - xe * cx[3] - he * ch[3] + bsum[3] + z;

            const float ig = sigmoidf_(g0);
            const float fg = sigmoidf_(g1);
            const float og = sigmoidf_(g2);
            const float ng = tanhf_(g3);

            const float cn = fg * cv[r] + ig * ng;
            const float hnv = og * tanhf_(cn);

            out[(size_t)brow * H_ + j] = hnv;
            out[(size_t)B_ * H_ + (size_t)brow * H_ + j] = cn;
        }

        if (mt < 7) {
#pragma unroll
            for (int ks = 0; ks < 4; ++ks) a[ks] = an[ks];
#pragma unroll
            for (int r = 0; r < 4; ++r) { xv[r] = xn[r]; hv[r] = hn[r]; cv[r] = cn2[r]; }
        }
    }
}

// ---------------------------------------------------------------------------
extern "C" void kernel_launch(void* const* d_in, const int* in_sizes, int n_in,
                              void* d_out, int out_size, void* d_ws, size_t ws_size,
                              hipStream_t stream) {
    const float* x     = (const float*)d_in[0];
    const float* h     = (const float*)d_in[1];
    const float* c     = (const float*)d_in[2];
    const float* u_x   = (const float*)d_in[3];
    const float* u_h   = (const float*)d_in[4];
    const float* v_x   = (const float*)d_in[5];
    const float* v_h   = (const float*)d_in[6];
    const float* b_x   = (const float*)d_in[7];
    const float* b_h   = (const float*)d_in[8];
    const float* dia_x = (const float*)d_in[9];
    const float* dia_h = (const float*)d_in[10];
    float* out = (float*)d_out;

    char* ws = (char*)d_ws;
    short* P      = (short*)(ws);                                    // 2,097,152 B
    short* uxT    = (short*)(ws + 2097152);                          //    65,536
    short* uhT    = (short*)(ws + 2097152 + 65536);                  //   131,072
    short* Vc     = (short*)(ws + 2097152 + 65536 + 131072);         // 1,048,576
    float* coef_x = (float*)(ws + 2097152 + 65536 + 131072 + 1048576);
    float* coef_h = (float*)(ws + 2097152 + 65536 + 131072 + 1048576 + 8192);

    prep_kernel<<<2816, 256, 0, stream>>>(u_x, u_h, v_x, v_h, uxT, uhT, Vc, coef_x, coef_h);
    stage1_kernel<<<dim3(512, 2), 256, 0, stream>>>(x, h, uxT, uhT, P);
    stage2_kernel<<<dim3(16, 64), 256, 0, stream>>>(P, Vc, x, h, c,
                                                    coef_x, coef_h, b_x, b_h,
                                                    dia_x, dia_h, out);
}

// Round 8
// 192.968 us; speedup vs baseline: 1.2153x; 1.0073x over previous
//
#include <hip/hip_runtime.h>
#include <hip/hip_bf16.h>

#define B_ 8192
#define I_ 512
#define H_ 1024
#define R_ 64

typedef __bf16 bf16x8 __attribute__((ext_vector_type(8)));
typedef short  s16x8  __attribute__((ext_vector_type(8)));
typedef float  f32x4  __attribute__((ext_vector_type(4)));

static __device__ __forceinline__ short f2bf(float f) {
    union { float f; unsigned u; } v; v.f = f;
    unsigned r = v.u + 0x7fffu + ((v.u >> 16) & 1u);
    return (short)(r >> 16);
}
static __device__ __forceinline__ float sigmoidf_(float v) {
    return 1.f / (1.f + __expf(-v));
}
static __device__ __forceinline__ float tanhf_(float v) {
    return 2.f / (1.f + __expf(-2.f * v)) - 1.f;
}

// ---------------------------------------------------------------------------
// Prep: uxT[64][512], uhT[64][1024], Vc[4096][128] (all bf16), coef_x[4][512],
// coef_h[4][1024] (f32). Coef section: one wave per j, lanes = rank r.
// 32768 + 65536 + 524288 + 98304 = 720896 = 2816 * 256 threads.
// ---------------------------------------------------------------------------
__global__ __launch_bounds__(256) void prep_kernel(
    const float* __restrict__ u_x, const float* __restrict__ u_h,
    const float* __restrict__ v_x, const float* __restrict__ v_h,
    short* __restrict__ uxT, short* __restrict__ uhT, short* __restrict__ Vc,
    float* __restrict__ coef_x, float* __restrict__ coef_h)
{
    int t = blockIdx.x * 256 + threadIdx.x;
    if (t < 64 * 512) {                       // uxT[r][k] = u_x[k][r], coalesced read
        int k = t >> 6, r = t & 63;
        uxT[r * 512 + k] = f2bf(u_x[t]);
        return;
    }
    t -= 64 * 512;
    if (t < 64 * 1024) {                      // uhT[r][k] = u_h[k][r]
        int k = t >> 6, r = t & 63;
        uhT[r * 1024 + k] = f2bf(u_h[t]);
        return;
    }
    t -= 64 * 1024;
    if (t < 4096 * 128) {                     // Vc = [v_x | v_h] rows, bf16
        int n = t >> 7, q = t & 127;
        Vc[t] = f2bf(q < 64 ? v_x[n * 64 + q] : v_h[n * 64 + (q - 64)]);
        return;
    }
    t -= 4096 * 128;
    if (t < 1536 * 64) {                      // coef: 1536 waves, one j each
        const int wid = t >> 6, lane = t & 63;
        const float* U; const float* V; float* C; int j, JN;
        if (wid < 512) { U = u_x; V = v_x; C = coef_x; j = wid;       JN = 512;  }
        else           { U = u_h; V = v_h; C = coef_h; j = wid - 512; JN = 1024; }
        const float uv = U[(size_t)j * 64 + lane];
        float s[4];
#pragma unroll
        for (int g = 0; g < 4; ++g)
            s[g] = uv * V[(size_t)(g * H_ + j) * 64 + lane];
#pragma unroll
        for (int off = 32; off >= 1; off >>= 1)
#pragma unroll
            for (int g = 0; g < 4; ++g)
                s[g] += __shfl_xor(s[g], off, 64);
        if (lane == 0)
#pragma unroll
            for (int g = 0; g < 4; ++g)
                C[g * JN + j] = s[g];
        return;
    }
}

// ---------------------------------------------------------------------------
// Stage 1: P[b][0:64] = x @ u_x, P[b][64:128] = h @ u_h  (bf16 MFMA).
// 256-thr blocks (4 waves), 16 batch rows per block -> grid (512, 2).
// ---------------------------------------------------------------------------
__global__ __launch_bounds__(256) void stage1_kernel(
    const float* __restrict__ x, const float* __restrict__ h,
    const short* __restrict__ uxT, const short* __restrict__ uhT,
    short* __restrict__ P)
{
    __shared__ short At[16 * 136];
    const int w = threadIdx.x >> 6, lane = threadIdx.x & 63;
    const int quad = lane >> 4, lr = lane & 15;
    const int n0 = w * 16;

    const float* X; const short* UT; int K, co;
    if (blockIdx.y == 0) { X = x; UT = uxT; K = I_; co = 0; }
    else                 { X = h; UT = uhT; K = H_; co = 64; }

    const int b0 = blockIdx.x * 16;
    const int srow = threadIdx.x >> 4;
    const int scol = (threadIdx.x & 15) * 8;

    f32x4 acc = {};
    const short* bp = UT + (size_t)(n0 + lr) * K + quad * 8;
    const short* arow = At + lr * 136 + quad * 8;
    const float* srcbase = X + (size_t)(b0 + srow) * K + scol;

    float4 c0 = ((const float4*)(srcbase))[0];
    float4 c1 = ((const float4*)(srcbase))[1];

    for (int k0 = 0; k0 < K; k0 += 128) {
        s16x8 p;
        p[0] = f2bf(c0.x); p[1] = f2bf(c0.y); p[2] = f2bf(c0.z); p[3] = f2bf(c0.w);
        p[4] = f2bf(c1.x); p[5] = f2bf(c1.y); p[6] = f2bf(c1.z); p[7] = f2bf(c1.w);
        __syncthreads();
        *(s16x8*)(At + srow * 136 + scol) = p;
        __syncthreads();
        if (k0 + 128 < K) {
            c0 = ((const float4*)(srcbase + k0 + 128))[0];
            c1 = ((const float4*)(srcbase + k0 + 128))[1];
        }
#pragma unroll
        for (int ks = 0; ks < 4; ++ks) {
            bf16x8 bfrag = *(const bf16x8*)(bp + k0 + ks * 32);
            bf16x8 afrag = *(const bf16x8*)(arow + ks * 32);
            acc = __builtin_amdgcn_mfma_f32_16x16x32_bf16(afrag, bfrag, acc, 0, 0, 0);
        }
    }

#pragma unroll
    for (int r = 0; r < 4; ++r)
        P[(size_t)(b0 + quad * 4 + r) * 128 + co + n0 + lr] = f2bf(acc[r]);
}

// ---------------------------------------------------------------------------
// Stage 2: gates = P @ Vc^T with fused LSTM epilogue.
// Single-wave 64-thr blocks, NO LDS, NO barriers. The wave's entire B operand
// (16 j x 4 gates x K=128 of Vc) is held in 64 VGPRs, loaded ONCE from
// L2-hot Vc and reused across all 8 m-tiles -> no ds_reads, no per-tile
// B re-gather (R6's mistake), no inter-wave coupling. A-frags (P, L2-hot)
// and epilogue x/h/c pipelined one m-tile ahead.
// Grid (B/128, H/16) = (64, 64) = 4096 independent waves.
// ---------------------------------------------------------------------------
__global__ __launch_bounds__(64) void stage2_kernel(
    const short* __restrict__ P, const short* __restrict__ Vc,
    const float* __restrict__ x, const float* __restrict__ h,
    const float* __restrict__ c,
    const float* __restrict__ coef_x, const float* __restrict__ coef_h,
    const float* __restrict__ b_x, const float* __restrict__ b_h,
    const float* __restrict__ dia_x, const float* __restrict__ dia_h,
    float* __restrict__ out)
{
    const int lane = threadIdx.x;
    const int quad = lane >> 4, lr = lane & 15;
    const int b0 = blockIdx.x * 128;
    const int j0 = blockIdx.y * 16;
    const int j = j0 + lr;
    const bool jx = (j < I_);

    // ---- B operand: 4 gates x 4 k-slices, resident in VGPRs for the wave's life
    bf16x8 bfr[4][4];
#pragma unroll
    for (int g = 0; g < 4; ++g)
#pragma unroll
        for (int ks = 0; ks < 4; ++ks)
            bfr[g][ks] = *(const bf16x8*)(Vc + (size_t)(g * H_ + j0 + lr) * 128 + ks * 32 + quad * 8);

    // per-j (lane-constant) small operands — L2-hot
    const float dx = jx ? dia_x[j] : 0.f;
    const float dh = dia_h[j];
    float cx[4], ch[4], bsum[4];
#pragma unroll
    for (int g = 0; g < 4; ++g) {
        cx[g]   = jx ? coef_x[g * I_ + j] : 0.f;
        ch[g]   = coef_h[g * H_ + j];
        bsum[g] = b_x[g * H_ + j] + b_h[g * H_ + j];
    }

    // prologue: A-fragments + epilogue operands for m-tile 0
    bf16x8 a[4];
#pragma unroll
    for (int ks = 0; ks < 4; ++ks)
        a[ks] = *(const bf16x8*)(P + (size_t)(b0 + lr) * 128 + ks * 32 + quad * 8);
    float xv[4], hv[4], cv[4];
#pragma unroll
    for (int r = 0; r < 4; ++r) {
        const int brow = b0 + quad * 4 + r;
        cv[r] = c[(size_t)brow * H_ + j];
        hv[r] = h[(size_t)brow * H_ + j];
        xv[r] = jx ? x[(size_t)brow * I_ + j] : 0.f;
    }

    for (int mt = 0; mt < 8; ++mt) {
        // prefetch next m-tile's A-fragments + epilogue operands
        bf16x8 an[4];
        float xn[4], hn[4], cn2[4];
        if (mt < 7) {
            const int rb = b0 + (mt + 1) * 16;
#pragma unroll
            for (int ks = 0; ks < 4; ++ks)
                an[ks] = *(const bf16x8*)(P + (size_t)(rb + lr) * 128 + ks * 32 + quad * 8);
#pragma unroll
            for (int r = 0; r < 4; ++r) {
                const int brow = rb + quad * 4 + r;
                cn2[r] = c[(size_t)brow * H_ + j];
                hn[r]  = h[(size_t)brow * H_ + j];
                xn[r]  = jx ? x[(size_t)brow * I_ + j] : 0.f;
            }
        }

        // MFMA: A and B both from registers — zero memory ops in the loop
        f32x4 acc[4] = {};
#pragma unroll
        for (int ks = 0; ks < 4; ++ks)
#pragma unroll
            for (int g = 0; g < 4; ++g)
                acc[g] = __builtin_amdgcn_mfma_f32_16x16x32_bf16(a[ks], bfr[g][ks], acc[g], 0, 0, 0);

        // epilogue for this m-tile
#pragma unroll
        for (int r = 0; r < 4; ++r) {
            const int brow = b0 + mt * 16 + quad * 4 + r;
            const float xe = xv[r], he = hv[r];
            const float z  = dx * xe + dh * he;

            const float g0 = acc[0][r] - xe * cx[0] - he * ch[0] + bsum[0] + z;
            const float g1 = acc[1][r] - xe * cx[1] - he * ch[1] + bsum[1] + z;
            const float g2 = acc[2][r] - xe * cx[2] - he * ch[2] + bsum[2] + z;
            const float g3 = acc[3][r] - xe * cx[3] - he * ch[3] + bsum[3] + z;

            const float ig = sigmoidf_(g0);
            const float fg = sigmoidf_(g1);
            const float og = sigmoidf_(g2);
            const float ng = tanhf_(g3);

            const float cn = fg * cv[r] + ig * ng;
            const float hnv = og * tanhf_(cn);

            out[(size_t)brow * H_ + j] = hnv;
            out[(size_t)B_ * H_ + (size_t)brow * H_ + j] = cn;
        }

        if (mt < 7) {
#pragma unroll
            for (int ks = 0; ks < 4; ++ks) a[ks] = an[ks];
#pragma unroll
            for (int r = 0; r < 4; ++r) { xv[r] = xn[r]; hv[r] = hn[r]; cv[r] = cn2[r]; }
        }
    }
}

// ---------------------------------------------------------------------------
extern "C" void kernel_launch(void* const* d_in, const int* in_sizes, int n_in,
                              void* d_out, int out_size, void* d_ws, size_t ws_size,
                              hipStream_t stream) {
    const float* x     = (const float*)d_in[0];
    const float* h     = (const float*)d_in[1];
    const float* c     = (const float*)d_in[2];
    const float* u_x   = (const float*)d_in[3];
    const float* u_h   = (const float*)d_in[4];
    const float* v_x   = (const float*)d_in[5];
    const float* v_h   = (const float*)d_in[6];
    const float* b_x   = (const float*)d_in[7];
    const float* b_h   = (const float*)d_in[8];
    const float* dia_x = (const float*)d_in[9];
    const float* dia_h = (const float*)d_in[10];
    float* out = (float*)d_out;

    char* ws = (char*)d_ws;
    short* P      = (short*)(ws);                                    // 2,097,152 B
    short* uxT    = (short*)(ws + 2097152);                          //    65,536
    short* uhT    = (short*)(ws + 2097152 + 65536);                  //   131,072
    short* Vc     = (short*)(ws + 2097152 + 65536 + 131072);         // 1,048,576
    float* coef_x = (float*)(ws + 2097152 + 65536 + 131072 + 1048576);
    float* coef_h = (float*)(ws + 2097152 + 65536 + 131072 + 1048576 + 8192);

    prep_kernel<<<2816, 256, 0, stream>>>(u_x, u_h, v_x, v_h, uxT, uhT, Vc, coef_x, coef_h);
    stage1_kernel<<<dim3(512, 2), 256, 0, stream>>>(x, h, uxT, uhT, P);
    stage2_kernel<<<dim3(64, 64), 64, 0, stream>>>(P, Vc, x, h, c,
                                                   coef_x, coef_h, b_x, b_h,
                                                   dia_x, dia_h, out);
}